// Round 15
// baseline (736.104 us; speedup 1.0000x reference)
//
#include <hip/hip_runtime.h>
#include <hip/hip_bf16.h>
#include <math.h>

#define G 4
#define S 2048
#define MDIM 1024
#define E 8
#define HDIM 4096
#define TOPK 2
#define CAP 640
#define GC (G*CAP)      /* 2560 rows per expert */
#define RBLK (G*S/4)    /* 2048 router blocks, 4 tokens each */

typedef __attribute__((ext_vector_type(8))) short bf16x8;
typedef __attribute__((ext_vector_type(4))) short s16x4;
typedef __attribute__((ext_vector_type(4))) float f32x4;
typedef __attribute__((ext_vector_type(16))) float f32x16;
typedef unsigned int u32;
typedef unsigned short u16;

#define MFMA32(a,b,c) __builtin_amdgcn_mfma_f32_32x32x16_bf16(a,b,c,0,0,0)
#define BAR() __builtin_amdgcn_s_barrier()

__device__ __forceinline__ u16 f2bf(float f) {
    union { float f; u32 u; } v; v.f = f;
    u32 r = v.u + 0x7fffu + ((v.u >> 16) & 1u);
    return (u16)(r >> 16);
}

__device__ __forceinline__ void gload16(const char* gp, char* lp) {
    __builtin_amdgcn_global_load_lds((const __attribute__((address_space(1))) u32*)gp,
                                     (__attribute__((address_space(3))) u32*)lp,
                                     16, 0, 0);
}

// 3-bit XOR swizzle for 128-byte LDS rows (involution; source+read sides)
__device__ __forceinline__ int swz128(int r) { return ((r >> 1) & 7) << 4; }

// ============ fused prep: router (blocks 0..2047) + 3 transposes ============
__device__ void transpose_body(const float* __restrict__ in, u16* __restrict__ out,
                               int R, int C, int tb, float (*tile)[68]) {
    int nbx = C / 64, nby = R / 64;
    int bx = tb % nbx, by = (tb / nbx) % nby, e = tb / (nbx * nby);
    const float* ine = in + (size_t)e * R * C;
    u16* oute = out + (size_t)e * R * C;
    int t = threadIdx.x;
    int x0 = bx * 64, y0 = by * 64;
    int lx = (t & 15) * 4, ly = t >> 4;
    #pragma unroll
    for (int i = 0; i < 4; ++i) {
        f32x4 v = *(const f32x4*)(ine + (size_t)(y0 + ly + i * 16) * C + x0 + lx);
        *(f32x4*)&tile[ly + i * 16][lx] = v;
    }
    __syncthreads();
    int rr0 = (t & 15) * 4, cb = t >> 4;
    #pragma unroll
    for (int p = 0; p < 4; ++p) {
        int cc = cb + p * 16;
        s16x4 pk;
        #pragma unroll
        for (int j = 0; j < 4; ++j) pk[j] = (short)f2bf(tile[rr0 + j][cc]);
        *(s16x4*)(oute + (size_t)(x0 + cc) * R + y0 + rr0) = pk;
    }
}

__global__ __launch_bounds__(256) void prep_kernel(
        const float* __restrict__ inp, const float* __restrict__ rw,
        const float* __restrict__ wi_gate, const float* __restrict__ wi_0,
        const float* __restrict__ wo,
        u16* __restrict__ WgT, u16* __restrict__ W0T, u16* __restrict__ WoT,
        int* __restrict__ top_i, float* __restrict__ top_p,
        float* __restrict__ partials) {
    __shared__ float tile[64][68];
    __shared__ float part[4][17];
    int bid = blockIdx.x;
    if (bid >= RBLK) {
        int tb = bid - RBLK;
        if (tb < 8192)       transpose_body(wi_gate, WgT, MDIM, HDIM, tb, tile);
        else if (tb < 16384) transpose_body(wi_0,   W0T, MDIM, HDIM, tb - 8192, tile);
        else                 transpose_body(wo,     WoT, HDIM, MDIM, tb - 16384, tile);
        return;
    }
    int wid = threadIdx.x >> 6, lane = threadIdx.x & 63;
    int tok = bid * 4 + wid;
    const float* x = inp + (size_t)tok * MDIM;
    float acc[E] = {0.f,0.f,0.f,0.f,0.f,0.f,0.f,0.f};
    #pragma unroll
    for (int rep = 0; rep < 4; ++rep) {
        int m0 = rep * 256 + lane * 4;
        f32x4 xv = *(const f32x4*)(x + m0);
        #pragma unroll
        for (int j = 0; j < 4; ++j) {
            const float* r = rw + (size_t)(m0 + j) * E;
            float xj = xv[j];
            #pragma unroll
            for (int e = 0; e < E; ++e) acc[e] += xj * r[e];
        }
    }
    #pragma unroll
    for (int e = 0; e < E; ++e)
        #pragma unroll
        for (int off = 32; off; off >>= 1) acc[e] += __shfl_down(acc[e], off);

    if (lane == 0) {
        float mx = acc[0];
        #pragma unroll
        for (int e = 1; e < E; ++e) mx = fmaxf(mx, acc[e]);
        float p[E], sum = 0.f;
        #pragma unroll
        for (int e = 0; e < E; ++e) { p[e] = expf(acc[e] - mx); sum += p[e]; }
        float inv = 1.f / sum;
        #pragma unroll
        for (int e = 0; e < E; ++e) p[e] *= inv;
        float lse = logf(sum) + mx;
        int i0 = 0;
        #pragma unroll
        for (int e = 1; e < E; ++e) if (acc[e] > acc[i0]) i0 = e;
        int i1 = (i0 == 0) ? 1 : 0;
        #pragma unroll
        for (int e = 0; e < E; ++e) if (e != i0 && acc[e] > acc[i1]) i1 = e;
        top_i[tok*2+0] = i0; top_i[tok*2+1] = i1;
        top_p[tok*2+0] = p[i0]; top_p[tok*2+1] = p[i1];
        #pragma unroll
        for (int e = 0; e < E; ++e) { part[wid][e] = p[e]; part[wid][8+e] = 0.f; }
        part[wid][8+i0] = 1.f; part[wid][8+i1] = 1.f;
        part[wid][16] = lse * lse;
    }
    __syncthreads();
    if (threadIdx.x < 17) {
        float v = part[0][threadIdx.x] + part[1][threadIdx.x] +
                  part[2][threadIdx.x] + part[3][threadIdx.x];
        partials[(size_t)bid * 17 + threadIdx.x] = v;
    }
}

// ============ fused scan (blocks 0..31) + reduce_partials (32..35) ============
// Writes ALL -1 sentinels itself (no host memsets needed).
__global__ __launch_bounds__(256) void scan_reduce_kernel(
        const int* __restrict__ top_i, const float* __restrict__ pad,
        const float* __restrict__ partials,
        int* __restrict__ slot_token, int* __restrict__ token_c,
        float* __restrict__ sums_out) {
    __shared__ int sums[256];
    __shared__ float red[256];
    int bid = blockIdx.x;
    int t = threadIdx.x;
    if (bid >= 32) {
        int g = bid - 32;
        float loc[17];
        #pragma unroll
        for (int c = 0; c < 17; ++c) loc[c] = 0.f;
        for (int r = t; r < 512; r += 256) {
            const float* pr = partials + ((size_t)g * 512 + r) * 17;
            #pragma unroll
            for (int c = 0; c < 17; ++c) loc[c] += pr[c];
        }
        for (int c = 0; c < 17; ++c) {
            red[t] = loc[c]; __syncthreads();
            for (int off = 128; off; off >>= 1) {
                if (t < off) red[t] += red[t + off];
                __syncthreads();
            }
            if (t == 0) sums_out[g * 17 + c] = red[0];
            __syncthreads();
        }
        return;
    }
    int g = bid >> 3, e = bid & 7;
    int base = t * 16;
    int run = 0; unsigned mask16 = 0, emask16 = 0; int loc[16];
    #pragma unroll
    for (int j = 0; j < 16; ++j) {
        int i = base + j; int s = i >> 1, k = i & 1;
        int ex = top_i[((size_t)(g * S + s)) * 2 + k];
        int me = (ex == e);
        int m = me && (pad[g * S + s] == 0.f);
        run += m; loc[j] = run;
        mask16 |= ((unsigned)m << j); emask16 |= ((unsigned)me << j);
    }
    sums[t] = run; __syncthreads();
    for (int off = 1; off < 256; off <<= 1) {
        int v = (t >= off) ? sums[t - off] : 0;
        __syncthreads();
        sums[t] += v;
        __syncthreads();
    }
    int excl = sums[t] - run;
    #pragma unroll
    for (int j = 0; j < 16; ++j) {
        int i = base + j; int s = i >> 1, k = i & 1;
        if ((mask16 >> j) & 1u) {
            int pos = excl + loc[j];
            if (pos <= CAP) {
                slot_token[((size_t)(e * G + g)) * CAP + (pos - 1)] = s;
                token_c[((size_t)(g * S + s)) * 2 + k] = pos - 1;
            } else {
                token_c[((size_t)(g * S + s)) * 2 + k] = -1;
            }
        } else if ((emask16 >> j) & 1u) {
            token_c[((size_t)(g * S + s)) * 2 + k] = -1;
        }
    }
    __syncthreads();
    int total = sums[255];
    for (int i = total + t; i < CAP; i += 256)
        slot_token[((size_t)(e * G + g)) * CAP + i] = -1;
}

// ---------------- gather tokens -> X bf16 [E][GC][MDIM] (2 rows/block) ------
__global__ __launch_bounds__(256) void gather_kernel(const float* __restrict__ inp,
                                                     const int* __restrict__ slot_token,
                                                     u16* __restrict__ X) {
    int row = blockIdx.x * 2 + (threadIdx.x >> 7);
    int t = threadIdx.x & 127;
    int s = slot_token[row];
    int g = (row % GC) / CAP;
    bf16x8 v;
    if (s >= 0) {
        const float* src = inp + ((size_t)(g * S + s)) * MDIM + t * 8;
        f32x4 a = *(const f32x4*)src;
        f32x4 b = *(const f32x4*)(src + 4);
        #pragma unroll
        for (int j = 0; j < 4; ++j) { v[j] = (short)f2bf(a[j]); v[4+j] = (short)f2bf(b[j]); }
    } else {
        #pragma unroll
        for (int j = 0; j < 8; ++j) v[j] = 0;
    }
    *(bf16x8*)(X + (size_t)row * MDIM + t * 8) = v;
}

// ======================================================================
// GEMM1+2 fused (R9 structure; block order now nt-FASTEST within expert:
// 32 consecutive resident blocks share ONE 512KB A-tile -> L2-resident,
// B re-reads absorbed by L3). 32x32x16, BM=256 BN=128 BK=64, ring-2 128KiB.
// ======================================================================
__global__ __launch_bounds__(512, 1) void gemm_ffn12_v9(
        const u16* __restrict__ Xb, const u16* __restrict__ WgT,
        const u16* __restrict__ W0T, u16* __restrict__ Hb) {
    extern __shared__ char smem[];
    const int NK = MDIM / 64;                      // 16
    int bid = blockIdx.x;
    int swz = (bid & 7) * 320 + (bid >> 3);        // bijective (2560 % 8 == 0)
    int e = swz / 320; int r320 = swz % 320;
    int mt = r320 >> 5, nt = r320 & 31;            // nt fastest
    const char* A  = (const char*)(Xb  + (size_t)e * GC * MDIM   + (size_t)mt * 256 * MDIM);
    const char* Bg = (const char*)(WgT + (size_t)e * HDIM * MDIM + (size_t)nt * 128 * MDIM);
    const char* B0 = (const char*)(W0T + (size_t)e * HDIM * MDIM + (size_t)nt * 128 * MDIM);
    int tid = threadIdx.x, w = tid >> 6, l = tid & 63;
    int wm = w >> 2, wn = w & 3;
    int lr = l & 31, lk = l >> 5;
    int lswz = ((lr >> 1) & 7) << 4;

    int koff[4];
    #pragma unroll
    for (int ks = 0; ks < 4; ++ks) koff[ks] = (ks * 32 + lk * 16) ^ lswz;
    int baseA[4];
    #pragma unroll
    for (int rb = 0; rb < 4; ++rb) baseA[rb] = (wm * 128 + rb * 32 + lr) * 128;
    int baseB = (wn * 32 + lr) * 128;

    const char* srcA[4]; const char* srcG[2]; const char* srcO[2];
    #pragma unroll
    for (int p = 0; p < 4; ++p) {
        int gr = p * 64 + w * 8 + (l >> 3);
        srcA[p] = A + (size_t)gr * (MDIM * 2) + (((l & 7) * 16) ^ swz128(gr));
    }
    #pragma unroll
    for (int p = 0; p < 2; ++p) {
        int gr = p * 64 + w * 8 + (l >> 3);
        srcG[p] = Bg + (size_t)gr * (MDIM * 2) + (((l & 7) * 16) ^ swz128(gr));
        srcO[p] = B0 + (size_t)gr * (MDIM * 2) + (((l & 7) * 16) ^ swz128(gr));
    }

    f32x16 zz;
    #pragma unroll
    for (int i = 0; i < 16; ++i) zz[i] = 0.f;
    f32x16 ag[4], ao[4];
    #pragma unroll
    for (int rb = 0; rb < 4; ++rb) { ag[rb] = zz; ao[rb] = zz; }

    auto stage = [&](int tt) {
        int kk = tt * 128;
        char* dst = smem + (tt & 1) * 65536;
        #pragma unroll
        for (int p = 0; p < 4; ++p)
            gload16(srcA[p] + kk, dst + (p * 64 + w * 8) * 128);
        #pragma unroll
        for (int p = 0; p < 2; ++p) {
            gload16(srcG[p] + kk, dst + 32768 + (p * 64 + w * 8) * 128);
            gload16(srcO[p] + kk, dst + 49152 + (p * 64 + w * 8) * 128);
        }
    };

    stage(0);
    asm volatile("s_waitcnt vmcnt(0)" ::: "memory");
    BAR();

    #pragma unroll 1
    for (int t = 0; t < NK; ++t) {
        if (t + 1 < NK) stage(t + 1);
        const char* bufc = smem + (t & 1) * 65536;
        #pragma unroll
        for (int ks = 0; ks < 4; ++ks) {
            bf16x8 bg = *(const bf16x8*)(bufc + 32768 + baseB + koff[ks]);
            bf16x8 bo = *(const bf16x8*)(bufc + 49152 + baseB + koff[ks]);
            bf16x8 af[4];
            #pragma unroll
            for (int rb = 0; rb < 4; ++rb)
                af[rb] = *(const bf16x8*)(bufc + baseA[rb] + koff[ks]);
            __builtin_amdgcn_s_setprio(1);
            #pragma unroll
            for (int rb = 0; rb < 4; ++rb) {
                ag[rb] = MFMA32(bg, af[rb], ag[rb]);
                ao[rb] = MFMA32(bo, af[rb], ao[rb]);
            }
            __builtin_amdgcn_s_setprio(0);
        }
        asm volatile("s_waitcnt vmcnt(0)" ::: "memory");
        BAR();
    }

    u16* He = Hb + (size_t)e * GC * HDIM;
    int row0 = mt * 256 + wm * 128 + lr;
    int col0 = nt * 128 + wn * 32 + lk * 4;
    #pragma unroll
    for (int rb = 0; rb < 4; ++rb) {
        size_t rowoff = (size_t)(row0 + rb * 32) * HDIM;
        #pragma unroll
        for (int q = 0; q < 4; ++q) {
            s16x4 pk;
            #pragma unroll
            for (int r = 0; r < 4; ++r) {
                float gv = ag[rb][q * 4 + r], ov = ao[rb][q * 4 + r];
                float hv = gv / (1.f + __expf(-gv)) * ov;
                pk[r] = (short)f2bf(hv);
            }
            *(s16x4*)(He + rowoff + col0 + q * 8) = pk;
        }
    }
}

// ======================================================================
// GEMM3 v10 (R14-proven): 32x32x16, BM=320 BN=256 BK=64 -> 256 blocks
// = exactly 1/CU, zero tail. ring-2 LDS 144KiB.
// ======================================================================
__global__ __launch_bounds__(512, 1) void gemm_out_v10(
        const u16* __restrict__ Hb, const u16* __restrict__ WoT,
        float* __restrict__ EO) {
    extern __shared__ char smem[];
    const int NK = HDIM / 64;                      // 64
    int bid = blockIdx.x;
    int swz = (bid & 7) * 32 + (bid >> 3);         // bijective (256 % 8 == 0)
    int e = swz >> 5; int rem = swz & 31; int mt = rem & 7; int nt = rem >> 3;
    const char* A = (const char*)(Hb  + (size_t)e * GC * HDIM   + (size_t)mt * 320 * HDIM);
    const char* B = (const char*)(WoT + (size_t)e * MDIM * HDIM + (size_t)nt * 256 * HDIM);
    int tid = threadIdx.x, w = tid >> 6, l = tid & 63;
    int wm = w >> 2, wn = w & 3;
    int lr = l & 31, lk = l >> 5;
    int lswz = ((lr >> 1) & 7) << 4;

    int koff[4];
    #pragma unroll
    for (int ks = 0; ks < 4; ++ks) koff[ks] = (ks * 32 + lk * 16) ^ lswz;
    int baseA[5], baseB[2];
    #pragma unroll
    for (int rb = 0; rb < 5; ++rb) baseA[rb] = (wm * 160 + rb * 32 + lr) * 128;
    #pragma unroll
    for (int cb = 0; cb < 2; ++cb) baseB[cb] = (wn * 64 + cb * 32 + lr) * 128;

    const char* srcA[5]; const char* srcB[4];
    #pragma unroll
    for (int p = 0; p < 5; ++p) {
        int gr = p * 64 + w * 8 + (l >> 3);
        srcA[p] = A + (size_t)gr * (HDIM * 2) + (((l & 7) * 16) ^ swz128(gr));
    }
    #pragma unroll
    for (int p = 0; p < 4; ++p) {
        int gr = p * 64 + w * 8 + (l >> 3);
        srcB[p] = B + (size_t)gr * (HDIM * 2) + (((l & 7) * 16) ^ swz128(gr));
    }

    f32x16 zz;
    #pragma unroll
    for (int i = 0; i < 16; ++i) zz[i] = 0.f;
    f32x16 acc[5][2];
    #pragma unroll
    for (int i = 0; i < 5; ++i)
        #pragma unroll
        for (int j = 0; j < 2; ++j) acc[i][j] = zz;

    auto stage = [&](int tt) {
        int kk = tt * 128;
        char* dst = smem + (tt & 1) * 73728;
        #pragma unroll
        for (int p = 0; p < 5; ++p)
            gload16(srcA[p] + kk, dst + (p * 64 + w * 8) * 128);
        #pragma unroll
        for (int p = 0; p < 4; ++p)
            gload16(srcB[p] + kk, dst + 40960 + (p * 64 + w * 8) * 128);
    };

    stage(0);
    asm volatile("s_waitcnt vmcnt(0)" ::: "memory");
    BAR();

    #pragma unroll 1
    for (int t = 0; t < NK; ++t) {
        if (t + 1 < NK) stage(t + 1);
        const char* bufc = smem + (t & 1) * 73728;
        #pragma unroll
        for (int ks = 0; ks < 4; ++ks) {
            bf16x8 bf[2], af[5];
            #pragma unroll
            for (int cb = 0; cb < 2; ++cb)
                bf[cb] = *(const bf16x8*)(bufc + 40960 + baseB[cb] + koff[ks]);
            #pragma unroll
            for (int rb = 0; rb < 5; ++rb)
                af[rb] = *(const bf16x8*)(bufc + baseA[rb] + koff[ks]);
            __builtin_amdgcn_s_setprio(1);
            #pragma unroll
            for (int rb = 0; rb < 5; ++rb)
                #pragma unroll
                for (int cb = 0; cb < 2; ++cb)
                    acc[rb][cb] = MFMA32(bf[cb], af[rb], acc[rb][cb]);
            __builtin_amdgcn_s_setprio(0);
        }
        asm volatile("s_waitcnt vmcnt(0)" ::: "memory");
        BAR();
    }

    float* Ee = EO + (size_t)e * GC * MDIM;
    int row0 = mt * 320 + wm * 160 + lr;
    int col0 = nt * 256 + wn * 64 + lk * 4;
    #pragma unroll
    for (int rb = 0; rb < 5; ++rb) {
        size_t rowoff = (size_t)(row0 + rb * 32) * MDIM;
        #pragma unroll
        for (int cb = 0; cb < 2; ++cb)
            #pragma unroll
            for (int q = 0; q < 4; ++q) {
                f32x4 v;
                #pragma unroll
                for (int r = 0; r < 4; ++r) v[r] = acc[rb][cb][q * 4 + r];
                *(f32x4*)(Ee + rowoff + col0 + cb * 32 + q * 8) = v;
            }
    }
}

// ============ combine (blocks 0..2047, 4 tokens each) + aux (block 2048) ====
__global__ __launch_bounds__(256) void combine_aux_kernel(
        const float* __restrict__ EO, const int* __restrict__ top_i,
        const float* __restrict__ top_p, const int* __restrict__ token_c,
        const float* __restrict__ sums, float* __restrict__ out) {
    int bid = blockIdx.x;
    if (bid == RBLK) {
        if (threadIdx.x == 0) {
            float lb = 0.f, z = 0.f;
            for (int g = 0; g < G; ++g) {
                for (int e = 0; e < E; ++e)
                    lb += (sums[g*17 + 8 + e] / (float)S) * (sums[g*17 + e] / (float)S);
                z += sums[g*17 + 16];
            }
            lb = lb / (float)(G * E) * (float)(E * E);
            z /= (float)(G * S);
            out[(size_t)G * S * MDIM] = 0.01f * lb + 0.001f * z;
        }
        return;
    }
    int t = threadIdx.x;
    #pragma unroll
    for (int tt = 0; tt < 4; ++tt) {
        int tok = bid * 4 + tt;
        int g = tok >> 11;
        f32x4 acc = {0.f, 0.f, 0.f, 0.f};
        #pragma unroll
        for (int k = 0; k < 2; ++k) {
            int c = token_c[tok * 2 + k];
            if (c >= 0) {
                int e = top_i[tok * 2 + k];
                float p = top_p[tok * 2 + k];
                const float* src = EO + ((size_t)e * GC + g * CAP + c) * MDIM + t * 4;
                f32x4 v = *(const f32x4*)src;
                #pragma unroll
                for (int j = 0; j < 4; ++j) acc[j] += p * v[j];
            }
        }
        *(f32x4*)(out + (size_t)tok * MDIM + t * 4) = acc;
    }
}

extern "C" void kernel_launch(void* const* d_in, const int* in_sizes, int n_in,
                              void* d_out, int out_size, void* d_ws, size_t ws_size,
                              hipStream_t stream) {
    (void)in_sizes; (void)n_in; (void)out_size; (void)ws_size;
    const float* inputs   = (const float*)d_in[0];
    const float* paddings = (const float*)d_in[1];
    const float* router_w = (const float*)d_in[2];
    const float* wi_gate  = (const float*)d_in[3];
    const float* wi_0     = (const float*)d_in[4];
    const float* wo       = (const float*)d_in[5];
    float* out = (float*)d_out;

    char* p = (char*)d_ws;
    u16* WgT = (u16*)p; p += (size_t)E * HDIM * MDIM * 2;
    u16* W0T = (u16*)p; p += (size_t)E * HDIM * MDIM * 2;
    u16* WoT = (u16*)p; p += (size_t)E * HDIM * MDIM * 2;
    u16* Xb  = (u16*)p; p += (size_t)E * GC * MDIM * 2;
    u16* Hb  = (u16*)p; p += (size_t)E * GC * HDIM * 2;
    float* EO = (float*)p; p += (size_t)E * GC * MDIM * 4;
    int*   top_i = (int*)p;   p += (size_t)G * S * TOPK * 4;
    float* top_p = (float*)p; p += (size_t)G * S * TOPK * 4;
    int*   token_c = (int*)p; p += (size_t)G * S * TOPK * 4;
    int*   slot_token = (int*)p; p += (size_t)E * G * CAP * 4;
    float* partials = (float*)p; p += (size_t)RBLK * 17 * 4;
    float* sums = (float*)p; p += 4 * 17 * 4;

    hipFuncSetAttribute((const void*)gemm_ffn12_v9,
                        hipFuncAttributeMaxDynamicSharedMemorySize, 131072);
    hipFuncSetAttribute((const void*)gemm_out_v10,
                        hipFuncAttributeMaxDynamicSharedMemorySize, 147456);

    // router (2048) + wi_gate T (8192) + wi_0 T (8192) + wo T (8192)
    prep_kernel<<<RBLK + 24576, 256, 0, stream>>>(inputs, router_w, wi_gate, wi_0, wo,
                                                  WgT, W0T, WoT, top_i, top_p, partials);
    // scan (32, writes all -1 sentinels) + reduce_partials (4)
    scan_reduce_kernel<<<36, 256, 0, stream>>>(top_i, paddings, partials,
                                               slot_token, token_c, sums);
    gather_kernel<<<E * GC / 2, 256, 0, stream>>>(inputs, slot_token, Xb);
    gemm_ffn12_v9<<<2560, 512, 131072, stream>>>(Xb, WgT, W0T, Hb);
    gemm_out_v10<<<256, 512, 147456, stream>>>(Hb, WoT, EO);
    // combine (2048 x 4 tokens) + aux_final (1)
    combine_aux_kernel<<<RBLK + 1, 256, 0, stream>>>(EO, top_i, top_p, token_c,
                                                     sums, out);
}

// Round 16
// 684.479 us; speedup vs baseline: 1.0754x; 1.0754x over previous
//
#include <hip/hip_runtime.h>
#include <hip/hip_bf16.h>
#include <math.h>

#define G 4
#define S 2048
#define MDIM 1024
#define E 8
#define HDIM 4096
#define TOPK 2
#define CAP 640
#define GC (G*CAP)      /* 2560 rows per expert */
#define RBLK (G*S/4)    /* 2048 router blocks, 4 tokens each */

typedef __attribute__((ext_vector_type(8))) short bf16x8;
typedef __attribute__((ext_vector_type(4))) short s16x4;
typedef __attribute__((ext_vector_type(4))) float f32x4;
typedef __attribute__((ext_vector_type(16))) float f32x16;
typedef unsigned int u32;
typedef unsigned short u16;

#define MFMA32(a,b,c) __builtin_amdgcn_mfma_f32_32x32x16_bf16(a,b,c,0,0,0)
#define BAR() __builtin_amdgcn_s_barrier()

__device__ __forceinline__ u16 f2bf(float f) {
    union { float f; u32 u; } v; v.f = f;
    u32 r = v.u + 0x7fffu + ((v.u >> 16) & 1u);
    return (u16)(r >> 16);
}

__device__ __forceinline__ void gload16(const char* gp, char* lp) {
    __builtin_amdgcn_global_load_lds((const __attribute__((address_space(1))) u32*)gp,
                                     (__attribute__((address_space(3))) u32*)lp,
                                     16, 0, 0);
}

// 3-bit XOR swizzle for 128-byte LDS rows (involution; source+read sides)
__device__ __forceinline__ int swz128(int r) { return ((r >> 1) & 7) << 4; }

// ============ fused prep: router (blocks 0..2047) + 3 transposes ============
__device__ void transpose_body(const float* __restrict__ in, u16* __restrict__ out,
                               int R, int C, int tb, float (*tile)[68]) {
    int nbx = C / 64, nby = R / 64;
    int bx = tb % nbx, by = (tb / nbx) % nby, e = tb / (nbx * nby);
    const float* ine = in + (size_t)e * R * C;
    u16* oute = out + (size_t)e * R * C;
    int t = threadIdx.x;
    int x0 = bx * 64, y0 = by * 64;
    int lx = (t & 15) * 4, ly = t >> 4;
    #pragma unroll
    for (int i = 0; i < 4; ++i) {
        f32x4 v = *(const f32x4*)(ine + (size_t)(y0 + ly + i * 16) * C + x0 + lx);
        *(f32x4*)&tile[ly + i * 16][lx] = v;
    }
    __syncthreads();
    int rr0 = (t & 15) * 4, cb = t >> 4;
    #pragma unroll
    for (int p = 0; p < 4; ++p) {
        int cc = cb + p * 16;
        s16x4 pk;
        #pragma unroll
        for (int j = 0; j < 4; ++j) pk[j] = (short)f2bf(tile[rr0 + j][cc]);
        *(s16x4*)(oute + (size_t)(x0 + cc) * R + y0 + rr0) = pk;
    }
}

__global__ __launch_bounds__(256) void prep_kernel(
        const float* __restrict__ inp, const float* __restrict__ rw,
        const float* __restrict__ wi_gate, const float* __restrict__ wi_0,
        const float* __restrict__ wo,
        u16* __restrict__ WgT, u16* __restrict__ W0T, u16* __restrict__ WoT,
        int* __restrict__ top_i, float* __restrict__ top_p,
        float* __restrict__ partials) {
    __shared__ float tile[64][68];
    __shared__ float part[4][17];
    int bid = blockIdx.x;
    if (bid >= RBLK) {
        int tb = bid - RBLK;
        if (tb < 8192)       transpose_body(wi_gate, WgT, MDIM, HDIM, tb, tile);
        else if (tb < 16384) transpose_body(wi_0,   W0T, MDIM, HDIM, tb - 8192, tile);
        else                 transpose_body(wo,     WoT, HDIM, MDIM, tb - 16384, tile);
        return;
    }
    int wid = threadIdx.x >> 6, lane = threadIdx.x & 63;
    int tok = bid * 4 + wid;
    const float* x = inp + (size_t)tok * MDIM;
    float acc[E] = {0.f,0.f,0.f,0.f,0.f,0.f,0.f,0.f};
    #pragma unroll
    for (int rep = 0; rep < 4; ++rep) {
        int m0 = rep * 256 + lane * 4;
        f32x4 xv = *(const f32x4*)(x + m0);
        #pragma unroll
        for (int j = 0; j < 4; ++j) {
            const float* r = rw + (size_t)(m0 + j) * E;
            float xj = xv[j];
            #pragma unroll
            for (int e = 0; e < E; ++e) acc[e] += xj * r[e];
        }
    }
    #pragma unroll
    for (int e = 0; e < E; ++e)
        #pragma unroll
        for (int off = 32; off; off >>= 1) acc[e] += __shfl_down(acc[e], off);

    if (lane == 0) {
        float mx = acc[0];
        #pragma unroll
        for (int e = 1; e < E; ++e) mx = fmaxf(mx, acc[e]);
        float p[E], sum = 0.f;
        #pragma unroll
        for (int e = 0; e < E; ++e) { p[e] = expf(acc[e] - mx); sum += p[e]; }
        float inv = 1.f / sum;
        #pragma unroll
        for (int e = 0; e < E; ++e) p[e] *= inv;
        float lse = logf(sum) + mx;
        int i0 = 0;
        #pragma unroll
        for (int e = 1; e < E; ++e) if (acc[e] > acc[i0]) i0 = e;
        int i1 = (i0 == 0) ? 1 : 0;
        #pragma unroll
        for (int e = 0; e < E; ++e) if (e != i0 && acc[e] > acc[i1]) i1 = e;
        top_i[tok*2+0] = i0; top_i[tok*2+1] = i1;
        top_p[tok*2+0] = p[i0]; top_p[tok*2+1] = p[i1];
        #pragma unroll
        for (int e = 0; e < E; ++e) { part[wid][e] = p[e]; part[wid][8+e] = 0.f; }
        part[wid][8+i0] = 1.f; part[wid][8+i1] = 1.f;
        part[wid][16] = lse * lse;
    }
    __syncthreads();
    if (threadIdx.x < 17) {
        float v = part[0][threadIdx.x] + part[1][threadIdx.x] +
                  part[2][threadIdx.x] + part[3][threadIdx.x];
        partials[(size_t)bid * 17 + threadIdx.x] = v;
    }
}

// ============ fused scan (blocks 0..31) + reduce_partials (32..35) ============
// Writes ALL -1 sentinels itself (no host memsets needed).
__global__ __launch_bounds__(256) void scan_reduce_kernel(
        const int* __restrict__ top_i, const float* __restrict__ pad,
        const float* __restrict__ partials,
        int* __restrict__ slot_token, int* __restrict__ token_c,
        float* __restrict__ sums_out) {
    __shared__ int sums[256];
    __shared__ float red[256];
    int bid = blockIdx.x;
    int t = threadIdx.x;
    if (bid >= 32) {
        int g = bid - 32;
        float loc[17];
        #pragma unroll
        for (int c = 0; c < 17; ++c) loc[c] = 0.f;
        for (int r = t; r < 512; r += 256) {
            const float* pr = partials + ((size_t)g * 512 + r) * 17;
            #pragma unroll
            for (int c = 0; c < 17; ++c) loc[c] += pr[c];
        }
        for (int c = 0; c < 17; ++c) {
            red[t] = loc[c]; __syncthreads();
            for (int off = 128; off; off >>= 1) {
                if (t < off) red[t] += red[t + off];
                __syncthreads();
            }
            if (t == 0) sums_out[g * 17 + c] = red[0];
            __syncthreads();
        }
        return;
    }
    int g = bid >> 3, e = bid & 7;
    int base = t * 16;
    int run = 0; unsigned mask16 = 0, emask16 = 0; int loc[16];
    #pragma unroll
    for (int j = 0; j < 16; ++j) {
        int i = base + j; int s = i >> 1, k = i & 1;
        int ex = top_i[((size_t)(g * S + s)) * 2 + k];
        int me = (ex == e);
        int m = me && (pad[g * S + s] == 0.f);
        run += m; loc[j] = run;
        mask16 |= ((unsigned)m << j); emask16 |= ((unsigned)me << j);
    }
    sums[t] = run; __syncthreads();
    for (int off = 1; off < 256; off <<= 1) {
        int v = (t >= off) ? sums[t - off] : 0;
        __syncthreads();
        sums[t] += v;
        __syncthreads();
    }
    int excl = sums[t] - run;
    #pragma unroll
    for (int j = 0; j < 16; ++j) {
        int i = base + j; int s = i >> 1, k = i & 1;
        if ((mask16 >> j) & 1u) {
            int pos = excl + loc[j];
            if (pos <= CAP) {
                slot_token[((size_t)(e * G + g)) * CAP + (pos - 1)] = s;
                token_c[((size_t)(g * S + s)) * 2 + k] = pos - 1;
            } else {
                token_c[((size_t)(g * S + s)) * 2 + k] = -1;
            }
        } else if ((emask16 >> j) & 1u) {
            token_c[((size_t)(g * S + s)) * 2 + k] = -1;
        }
    }
    __syncthreads();
    int total = sums[255];
    for (int i = total + t; i < CAP; i += 256)
        slot_token[((size_t)(e * G + g)) * CAP + i] = -1;
}

// ---------------- gather tokens -> X bf16 [E][GC][MDIM] ----------------
__global__ __launch_bounds__(128) void gather_kernel(const float* __restrict__ inp,
                                                     const int* __restrict__ slot_token,
                                                     u16* __restrict__ X) {
    int row = blockIdx.x;
    int t = threadIdx.x;
    int s = slot_token[row];
    int g = (row % GC) / CAP;
    bf16x8 v;
    if (s >= 0) {
        const float* src = inp + ((size_t)(g * S + s)) * MDIM + t * 8;
        f32x4 a = *(const f32x4*)src;
        f32x4 b = *(const f32x4*)(src + 4);
        #pragma unroll
        for (int j = 0; j < 4; ++j) { v[j] = (short)f2bf(a[j]); v[4+j] = (short)f2bf(b[j]); }
    } else {
        #pragma unroll
        for (int j = 0; j < 8; ++j) v[j] = 0;
    }
    *(bf16x8*)(X + (size_t)row * MDIM + t * 8) = v;
}

// ======================================================================
// GEMM1+2 fused (R9-proven, mt-fastest order): 32x32x16, BM=256 BN=128
// BK=64, ring-2 LDS 128KiB, stage(t+1) || compute(t), vmcnt(0)+barrier/tile.
// ======================================================================
__global__ __launch_bounds__(512, 1) void gemm_ffn12_v9(
        const u16* __restrict__ Xb, const u16* __restrict__ WgT,
        const u16* __restrict__ W0T, u16* __restrict__ Hb) {
    extern __shared__ char smem[];
    const int NK = MDIM / 64;                      // 16
    int bid = blockIdx.x;
    int swz = (bid & 7) * 320 + (bid >> 3);        // bijective (2560 % 8 == 0)
    int mt = swz % 10, nt = (swz / 10) & 31, e = swz / 320;
    const char* A  = (const char*)(Xb  + (size_t)e * GC * MDIM   + (size_t)mt * 256 * MDIM);
    const char* Bg = (const char*)(WgT + (size_t)e * HDIM * MDIM + (size_t)nt * 128 * MDIM);
    const char* B0 = (const char*)(W0T + (size_t)e * HDIM * MDIM + (size_t)nt * 128 * MDIM);
    int tid = threadIdx.x, w = tid >> 6, l = tid & 63;
    int wm = w >> 2, wn = w & 3;
    int lr = l & 31, lk = l >> 5;
    int lswz = ((lr >> 1) & 7) << 4;

    int koff[4];
    #pragma unroll
    for (int ks = 0; ks < 4; ++ks) koff[ks] = (ks * 32 + lk * 16) ^ lswz;
    int baseA[4];
    #pragma unroll
    for (int rb = 0; rb < 4; ++rb) baseA[rb] = (wm * 128 + rb * 32 + lr) * 128;
    int baseB = (wn * 32 + lr) * 128;

    const char* srcA[4]; const char* srcG[2]; const char* srcO[2];
    #pragma unroll
    for (int p = 0; p < 4; ++p) {
        int gr = p * 64 + w * 8 + (l >> 3);
        srcA[p] = A + (size_t)gr * (MDIM * 2) + (((l & 7) * 16) ^ swz128(gr));
    }
    #pragma unroll
    for (int p = 0; p < 2; ++p) {
        int gr = p * 64 + w * 8 + (l >> 3);
        srcG[p] = Bg + (size_t)gr * (MDIM * 2) + (((l & 7) * 16) ^ swz128(gr));
        srcO[p] = B0 + (size_t)gr * (MDIM * 2) + (((l & 7) * 16) ^ swz128(gr));
    }

    f32x16 zz;
    #pragma unroll
    for (int i = 0; i < 16; ++i) zz[i] = 0.f;
    f32x16 ag[4], ao[4];
    #pragma unroll
    for (int rb = 0; rb < 4; ++rb) { ag[rb] = zz; ao[rb] = zz; }

    auto stage = [&](int tt) {
        int kk = tt * 128;
        char* dst = smem + (tt & 1) * 65536;
        #pragma unroll
        for (int p = 0; p < 4; ++p)
            gload16(srcA[p] + kk, dst + (p * 64 + w * 8) * 128);
        #pragma unroll
        for (int p = 0; p < 2; ++p) {
            gload16(srcG[p] + kk, dst + 32768 + (p * 64 + w * 8) * 128);
            gload16(srcO[p] + kk, dst + 49152 + (p * 64 + w * 8) * 128);
        }
    };

    stage(0);
    asm volatile("s_waitcnt vmcnt(0)" ::: "memory");
    BAR();

    #pragma unroll 1
    for (int t = 0; t < NK; ++t) {
        if (t + 1 < NK) stage(t + 1);
        const char* bufc = smem + (t & 1) * 65536;
        #pragma unroll
        for (int ks = 0; ks < 4; ++ks) {
            bf16x8 bg = *(const bf16x8*)(bufc + 32768 + baseB + koff[ks]);
            bf16x8 bo = *(const bf16x8*)(bufc + 49152 + baseB + koff[ks]);
            bf16x8 af[4];
            #pragma unroll
            for (int rb = 0; rb < 4; ++rb)
                af[rb] = *(const bf16x8*)(bufc + baseA[rb] + koff[ks]);
            __builtin_amdgcn_s_setprio(1);
            #pragma unroll
            for (int rb = 0; rb < 4; ++rb) {
                ag[rb] = MFMA32(bg, af[rb], ag[rb]);
                ao[rb] = MFMA32(bo, af[rb], ao[rb]);
            }
            __builtin_amdgcn_s_setprio(0);
        }
        asm volatile("s_waitcnt vmcnt(0)" ::: "memory");
        BAR();
    }

    u16* He = Hb + (size_t)e * GC * HDIM;
    int row0 = mt * 256 + wm * 128 + lr;
    int col0 = nt * 128 + wn * 32 + lk * 4;
    #pragma unroll
    for (int rb = 0; rb < 4; ++rb) {
        size_t rowoff = (size_t)(row0 + rb * 32) * HDIM;
        #pragma unroll
        for (int q = 0; q < 4; ++q) {
            s16x4 pk;
            #pragma unroll
            for (int r = 0; r < 4; ++r) {
                float gv = ag[rb][q * 4 + r], ov = ao[rb][q * 4 + r];
                float hv = gv / (1.f + __expf(-gv)) * ov;
                pk[r] = (short)f2bf(hv);
            }
            *(s16x4*)(He + rowoff + col0 + q * 8) = pk;
        }
    }
}

// ======================================================================
// GEMM3 v10 (R14-proven): 32x32x16, BM=320 BN=256 BK=64 -> 256 blocks
// = exactly 1/CU, zero tail. ring-2 LDS 144KiB.
// ======================================================================
__global__ __launch_bounds__(512, 1) void gemm_out_v10(
        const u16* __restrict__ Hb, const u16* __restrict__ WoT,
        float* __restrict__ EO) {
    extern __shared__ char smem[];
    const int NK = HDIM / 64;                      // 64
    int bid = blockIdx.x;
    int swz = (bid & 7) * 32 + (bid >> 3);         // bijective (256 % 8 == 0)
    int e = swz >> 5; int rem = swz & 31; int mt = rem & 7; int nt = rem >> 3;
    const char* A = (const char*)(Hb  + (size_t)e * GC * HDIM   + (size_t)mt * 320 * HDIM);
    const char* B = (const char*)(WoT + (size_t)e * MDIM * HDIM + (size_t)nt * 256 * HDIM);
    int tid = threadIdx.x, w = tid >> 6, l = tid & 63;
    int wm = w >> 2, wn = w & 3;
    int lr = l & 31, lk = l >> 5;
    int lswz = ((lr >> 1) & 7) << 4;

    int koff[4];
    #pragma unroll
    for (int ks = 0; ks < 4; ++ks) koff[ks] = (ks * 32 + lk * 16) ^ lswz;
    int baseA[5], baseB[2];
    #pragma unroll
    for (int rb = 0; rb < 5; ++rb) baseA[rb] = (wm * 160 + rb * 32 + lr) * 128;
    #pragma unroll
    for (int cb = 0; cb < 2; ++cb) baseB[cb] = (wn * 64 + cb * 32 + lr) * 128;

    const char* srcA[5]; const char* srcB[4];
    #pragma unroll
    for (int p = 0; p < 5; ++p) {
        int gr = p * 64 + w * 8 + (l >> 3);
        srcA[p] = A + (size_t)gr * (HDIM * 2) + (((l & 7) * 16) ^ swz128(gr));
    }
    #pragma unroll
    for (int p = 0; p < 4; ++p) {
        int gr = p * 64 + w * 8 + (l >> 3);
        srcB[p] = B + (size_t)gr * (HDIM * 2) + (((l & 7) * 16) ^ swz128(gr));
    }

    f32x16 zz;
    #pragma unroll
    for (int i = 0; i < 16; ++i) zz[i] = 0.f;
    f32x16 acc[5][2];
    #pragma unroll
    for (int i = 0; i < 5; ++i)
        #pragma unroll
        for (int j = 0; j < 2; ++j) acc[i][j] = zz;

    auto stage = [&](int tt) {
        int kk = tt * 128;
        char* dst = smem + (tt & 1) * 73728;
        #pragma unroll
        for (int p = 0; p < 5; ++p)
            gload16(srcA[p] + kk, dst + (p * 64 + w * 8) * 128);
        #pragma unroll
        for (int p = 0; p < 4; ++p)
            gload16(srcB[p] + kk, dst + 40960 + (p * 64 + w * 8) * 128);
    };

    stage(0);
    asm volatile("s_waitcnt vmcnt(0)" ::: "memory");
    BAR();

    #pragma unroll 1
    for (int t = 0; t < NK; ++t) {
        if (t + 1 < NK) stage(t + 1);
        const char* bufc = smem + (t & 1) * 73728;
        #pragma unroll
        for (int ks = 0; ks < 4; ++ks) {
            bf16x8 bf[2], af[5];
            #pragma unroll
            for (int cb = 0; cb < 2; ++cb)
                bf[cb] = *(const bf16x8*)(bufc + 40960 + baseB[cb] + koff[ks]);
            #pragma unroll
            for (int rb = 0; rb < 5; ++rb)
                af[rb] = *(const bf16x8*)(bufc + baseA[rb] + koff[ks]);
            __builtin_amdgcn_s_setprio(1);
            #pragma unroll
            for (int rb = 0; rb < 5; ++rb)
                #pragma unroll
                for (int cb = 0; cb < 2; ++cb)
                    acc[rb][cb] = MFMA32(bf[cb], af[rb], acc[rb][cb]);
            __builtin_amdgcn_s_setprio(0);
        }
        asm volatile("s_waitcnt vmcnt(0)" ::: "memory");
        BAR();
    }

    float* Ee = EO + (size_t)e * GC * MDIM;
    int row0 = mt * 320 + wm * 160 + lr;
    int col0 = nt * 256 + wn * 64 + lk * 4;
    #pragma unroll
    for (int rb = 0; rb < 5; ++rb) {
        size_t rowoff = (size_t)(row0 + rb * 32) * MDIM;
        #pragma unroll
        for (int cb = 0; cb < 2; ++cb)
            #pragma unroll
            for (int q = 0; q < 4; ++q) {
                f32x4 v;
                #pragma unroll
                for (int r = 0; r < 4; ++r) v[r] = acc[rb][cb][q * 4 + r];
                *(f32x4*)(Ee + rowoff + col0 + cb * 32 + q * 8) = v;
            }
    }
}

// ============ combine (blocks 0..8191) + aux_final (block 8192) ============
__global__ __launch_bounds__(256) void combine_aux_kernel(
        const float* __restrict__ EO, const int* __restrict__ top_i,
        const float* __restrict__ top_p, const int* __restrict__ token_c,
        const float* __restrict__ sums, float* __restrict__ out) {
    int bid = blockIdx.x;
    if (bid == G * S) {
        if (threadIdx.x == 0) {
            float lb = 0.f, z = 0.f;
            for (int g = 0; g < G; ++g) {
                for (int e = 0; e < E; ++e)
                    lb += (sums[g*17 + 8 + e] / (float)S) * (sums[g*17 + e] / (float)S);
                z += sums[g*17 + 16];
            }
            lb = lb / (float)(G * E) * (float)(E * E);
            z /= (float)(G * S);
            out[(size_t)G * S * MDIM] = 0.01f * lb + 0.001f * z;
        }
        return;
    }
    int tok = bid, t = threadIdx.x;
    int g = tok >> 11;
    f32x4 acc = {0.f, 0.f, 0.f, 0.f};
    #pragma unroll
    for (int k = 0; k < 2; ++k) {
        int c = token_c[tok * 2 + k];
        if (c >= 0) {
            int e = top_i[tok * 2 + k];
            float p = top_p[tok * 2 + k];
            const float* src = EO + ((size_t)e * GC + g * CAP + c) * MDIM + t * 4;
            f32x4 v = *(const f32x4*)src;
            #pragma unroll
            for (int j = 0; j < 4; ++j) acc[j] += p * v[j];
        }
    }
    *(f32x4*)(out + (size_t)tok * MDIM + t * 4) = acc;
}

extern "C" void kernel_launch(void* const* d_in, const int* in_sizes, int n_in,
                              void* d_out, int out_size, void* d_ws, size_t ws_size,
                              hipStream_t stream) {
    (void)in_sizes; (void)n_in; (void)out_size; (void)ws_size;
    const float* inputs   = (const float*)d_in[0];
    const float* paddings = (const float*)d_in[1];
    const float* router_w = (const float*)d_in[2];
    const float* wi_gate  = (const float*)d_in[3];
    const float* wi_0     = (const float*)d_in[4];
    const float* wo       = (const float*)d_in[5];
    float* out = (float*)d_out;

    char* p = (char*)d_ws;
    u16* WgT = (u16*)p; p += (size_t)E * HDIM * MDIM * 2;
    u16* W0T = (u16*)p; p += (size_t)E * HDIM * MDIM * 2;
    u16* WoT = (u16*)p; p += (size_t)E * HDIM * MDIM * 2;
    u16* Xb  = (u16*)p; p += (size_t)E * GC * MDIM * 2;
    u16* Hb  = (u16*)p; p += (size_t)E * GC * HDIM * 2;
    float* EO = (float*)p; p += (size_t)E * GC * MDIM * 4;
    int*   top_i = (int*)p;   p += (size_t)G * S * TOPK * 4;
    float* top_p = (float*)p; p += (size_t)G * S * TOPK * 4;
    int*   token_c = (int*)p; p += (size_t)G * S * TOPK * 4;
    int*   slot_token = (int*)p; p += (size_t)E * G * CAP * 4;
    float* partials = (float*)p; p += (size_t)RBLK * 17 * 4;
    float* sums = (float*)p; p += 4 * 17 * 4;

    hipFuncSetAttribute((const void*)gemm_ffn12_v9,
                        hipFuncAttributeMaxDynamicSharedMemorySize, 131072);
    hipFuncSetAttribute((const void*)gemm_out_v10,
                        hipFuncAttributeMaxDynamicSharedMemorySize, 147456);

    // router (2048) + wi_gate T (8192) + wi_0 T (8192) + wo T (8192)
    prep_kernel<<<RBLK + 24576, 256, 0, stream>>>(inputs, router_w, wi_gate, wi_0, wo,
                                                  WgT, W0T, WoT, top_i, top_p, partials);
    // scan (32, writes all -1 sentinels) + reduce_partials (4)
    scan_reduce_kernel<<<36, 256, 0, stream>>>(top_i, paddings, partials,
                                               slot_token, token_c, sums);
    gather_kernel<<<E * GC, 128, 0, stream>>>(inputs, slot_token, Xb);
    gemm_ffn12_v9<<<2560, 512, 131072, stream>>>(Xb, WgT, W0T, Hb);
    gemm_out_v10<<<256, 512, 147456, stream>>>(Hb, WoT, EO);
    // combine (8192) + aux_final (1)
    combine_aux_kernel<<<G * S + 1, 256, 0, stream>>>(EO, top_i, top_p, token_c,
                                                      sums, out);
}

// Round 17
// 680.043 us; speedup vs baseline: 1.0824x; 1.0065x over previous
//
#include <hip/hip_runtime.h>
#include <hip/hip_bf16.h>
#include <math.h>

#define G 4
#define S 2048
#define MDIM 1024
#define E 8
#define HDIM 4096
#define TOPK 2
#define CAP 640
#define GC (G*CAP)      /* 2560 rows per expert */
#define RBLK (G*S/4)    /* 2048 router blocks, 4 tokens each */

typedef __attribute__((ext_vector_type(8))) short bf16x8;
typedef __attribute__((ext_vector_type(4))) short s16x4;
typedef __attribute__((ext_vector_type(4))) float f32x4;
typedef __attribute__((ext_vector_type(16))) float f32x16;
typedef unsigned int u32;
typedef unsigned short u16;

#define MFMA32(a,b,c) __builtin_amdgcn_mfma_f32_32x32x16_bf16(a,b,c,0,0,0)
#define BAR() __builtin_amdgcn_s_barrier()

__device__ __forceinline__ u16 f2bf(float f) {
    union { float f; u32 u; } v; v.f = f;
    u32 r = v.u + 0x7fffu + ((v.u >> 16) & 1u);
    return (u16)(r >> 16);
}

__device__ __forceinline__ float bf2f(u16 b) {
    union { u32 u; float f; } v; v.u = ((u32)b) << 16;
    return v.f;
}

__device__ __forceinline__ void gload16(const char* gp, char* lp) {
    __builtin_amdgcn_global_load_lds((const __attribute__((address_space(1))) u32*)gp,
                                     (__attribute__((address_space(3))) u32*)lp,
                                     16, 0, 0);
}

// 3-bit XOR swizzle for 128-byte LDS rows (involution; source+read sides)
__device__ __forceinline__ int swz128(int r) { return ((r >> 1) & 7) << 4; }

// ============ fused prep: router (blocks 0..2047) + 3 transposes ============
__device__ void transpose_body(const float* __restrict__ in, u16* __restrict__ out,
                               int R, int C, int tb, float (*tile)[68]) {
    int nbx = C / 64, nby = R / 64;
    int bx = tb % nbx, by = (tb / nbx) % nby, e = tb / (nbx * nby);
    const float* ine = in + (size_t)e * R * C;
    u16* oute = out + (size_t)e * R * C;
    int t = threadIdx.x;
    int x0 = bx * 64, y0 = by * 64;
    int lx = (t & 15) * 4, ly = t >> 4;
    #pragma unroll
    for (int i = 0; i < 4; ++i) {
        f32x4 v = *(const f32x4*)(ine + (size_t)(y0 + ly + i * 16) * C + x0 + lx);
        *(f32x4*)&tile[ly + i * 16][lx] = v;
    }
    __syncthreads();
    int rr0 = (t & 15) * 4, cb = t >> 4;
    #pragma unroll
    for (int p = 0; p < 4; ++p) {
        int cc = cb + p * 16;
        s16x4 pk;
        #pragma unroll
        for (int j = 0; j < 4; ++j) pk[j] = (short)f2bf(tile[rr0 + j][cc]);
        *(s16x4*)(oute + (size_t)(x0 + cc) * R + y0 + rr0) = pk;
    }
}

__global__ __launch_bounds__(256) void prep_kernel(
        const float* __restrict__ inp, const float* __restrict__ rw,
        const float* __restrict__ wi_gate, const float* __restrict__ wi_0,
        const float* __restrict__ wo,
        u16* __restrict__ WgT, u16* __restrict__ W0T, u16* __restrict__ WoT,
        int* __restrict__ top_i, float* __restrict__ top_p,
        float* __restrict__ partials) {
    __shared__ float tile[64][68];
    __shared__ float part[4][17];
    int bid = blockIdx.x;
    if (bid >= RBLK) {
        int tb = bid - RBLK;
        if (tb < 8192)       transpose_body(wi_gate, WgT, MDIM, HDIM, tb, tile);
        else if (tb < 16384) transpose_body(wi_0,   W0T, MDIM, HDIM, tb - 8192, tile);
        else                 transpose_body(wo,     WoT, HDIM, MDIM, tb - 16384, tile);
        return;
    }
    int wid = threadIdx.x >> 6, lane = threadIdx.x & 63;
    int tok = bid * 4 + wid;
    const float* x = inp + (size_t)tok * MDIM;
    float acc[E] = {0.f,0.f,0.f,0.f,0.f,0.f,0.f,0.f};
    #pragma unroll
    for (int rep = 0; rep < 4; ++rep) {
        int m0 = rep * 256 + lane * 4;
        f32x4 xv = *(const f32x4*)(x + m0);
        #pragma unroll
        for (int j = 0; j < 4; ++j) {
            const float* r = rw + (size_t)(m0 + j) * E;
            float xj = xv[j];
            #pragma unroll
            for (int e = 0; e < E; ++e) acc[e] += xj * r[e];
        }
    }
    #pragma unroll
    for (int e = 0; e < E; ++e)
        #pragma unroll
        for (int off = 32; off; off >>= 1) acc[e] += __shfl_down(acc[e], off);

    if (lane == 0) {
        float mx = acc[0];
        #pragma unroll
        for (int e = 1; e < E; ++e) mx = fmaxf(mx, acc[e]);
        float p[E], sum = 0.f;
        #pragma unroll
        for (int e = 0; e < E; ++e) { p[e] = expf(acc[e] - mx); sum += p[e]; }
        float inv = 1.f / sum;
        #pragma unroll
        for (int e = 0; e < E; ++e) p[e] *= inv;
        float lse = logf(sum) + mx;
        int i0 = 0;
        #pragma unroll
        for (int e = 1; e < E; ++e) if (acc[e] > acc[i0]) i0 = e;
        int i1 = (i0 == 0) ? 1 : 0;
        #pragma unroll
        for (int e = 0; e < E; ++e) if (e != i0 && acc[e] > acc[i1]) i1 = e;
        top_i[tok*2+0] = i0; top_i[tok*2+1] = i1;
        top_p[tok*2+0] = p[i0]; top_p[tok*2+1] = p[i1];
        #pragma unroll
        for (int e = 0; e < E; ++e) { part[wid][e] = p[e]; part[wid][8+e] = 0.f; }
        part[wid][8+i0] = 1.f; part[wid][8+i1] = 1.f;
        part[wid][16] = lse * lse;
    }
    __syncthreads();
    if (threadIdx.x < 17) {
        float v = part[0][threadIdx.x] + part[1][threadIdx.x] +
                  part[2][threadIdx.x] + part[3][threadIdx.x];
        partials[(size_t)bid * 17 + threadIdx.x] = v;
    }
}

// ============ fused scan (blocks 0..31) + reduce_partials (32..35) ============
// Writes ALL -1 sentinels itself (no host memsets needed).
__global__ __launch_bounds__(256) void scan_reduce_kernel(
        const int* __restrict__ top_i, const float* __restrict__ pad,
        const float* __restrict__ partials,
        int* __restrict__ slot_token, int* __restrict__ token_c,
        float* __restrict__ sums_out) {
    __shared__ int sums[256];
    __shared__ float red[256];
    int bid = blockIdx.x;
    int t = threadIdx.x;
    if (bid >= 32) {
        int g = bid - 32;
        float loc[17];
        #pragma unroll
        for (int c = 0; c < 17; ++c) loc[c] = 0.f;
        for (int r = t; r < 512; r += 256) {
            const float* pr = partials + ((size_t)g * 512 + r) * 17;
            #pragma unroll
            for (int c = 0; c < 17; ++c) loc[c] += pr[c];
        }
        for (int c = 0; c < 17; ++c) {
            red[t] = loc[c]; __syncthreads();
            for (int off = 128; off; off >>= 1) {
                if (t < off) red[t] += red[t + off];
                __syncthreads();
            }
            if (t == 0) sums_out[g * 17 + c] = red[0];
            __syncthreads();
        }
        return;
    }
    int g = bid >> 3, e = bid & 7;
    int base = t * 16;
    int run = 0; unsigned mask16 = 0, emask16 = 0; int loc[16];
    #pragma unroll
    for (int j = 0; j < 16; ++j) {
        int i = base + j; int s = i >> 1, k = i & 1;
        int ex = top_i[((size_t)(g * S + s)) * 2 + k];
        int me = (ex == e);
        int m = me && (pad[g * S + s] == 0.f);
        run += m; loc[j] = run;
        mask16 |= ((unsigned)m << j); emask16 |= ((unsigned)me << j);
    }
    sums[t] = run; __syncthreads();
    for (int off = 1; off < 256; off <<= 1) {
        int v = (t >= off) ? sums[t - off] : 0;
        __syncthreads();
        sums[t] += v;
        __syncthreads();
    }
    int excl = sums[t] - run;
    #pragma unroll
    for (int j = 0; j < 16; ++j) {
        int i = base + j; int s = i >> 1, k = i & 1;
        if ((mask16 >> j) & 1u) {
            int pos = excl + loc[j];
            if (pos <= CAP) {
                slot_token[((size_t)(e * G + g)) * CAP + (pos - 1)] = s;
                token_c[((size_t)(g * S + s)) * 2 + k] = pos - 1;
            } else {
                token_c[((size_t)(g * S + s)) * 2 + k] = -1;
            }
        } else if ((emask16 >> j) & 1u) {
            token_c[((size_t)(g * S + s)) * 2 + k] = -1;
        }
    }
    __syncthreads();
    int total = sums[255];
    for (int i = total + t; i < CAP; i += 256)
        slot_token[((size_t)(e * G + g)) * CAP + i] = -1;
}

// ---------------- gather tokens -> X bf16 [E][GC][MDIM] ----------------
__global__ __launch_bounds__(128) void gather_kernel(const float* __restrict__ inp,
                                                     const int* __restrict__ slot_token,
                                                     u16* __restrict__ X) {
    int row = blockIdx.x;
    int t = threadIdx.x;
    int s = slot_token[row];
    int g = (row % GC) / CAP;
    bf16x8 v;
    if (s >= 0) {
        const float* src = inp + ((size_t)(g * S + s)) * MDIM + t * 8;
        f32x4 a = *(const f32x4*)src;
        f32x4 b = *(const f32x4*)(src + 4);
        #pragma unroll
        for (int j = 0; j < 4; ++j) { v[j] = (short)f2bf(a[j]); v[4+j] = (short)f2bf(b[j]); }
    } else {
        #pragma unroll
        for (int j = 0; j < 8; ++j) v[j] = 0;
    }
    *(bf16x8*)(X + (size_t)row * MDIM + t * 8) = v;
}

// ======================================================================
// GEMM1+2 fused (R9-proven, mt-fastest order): 32x32x16, BM=256 BN=128
// BK=64, ring-2 LDS 128KiB, stage(t+1) || compute(t), vmcnt(0)+barrier/tile.
// ======================================================================
__global__ __launch_bounds__(512, 1) void gemm_ffn12_v9(
        const u16* __restrict__ Xb, const u16* __restrict__ WgT,
        const u16* __restrict__ W0T, u16* __restrict__ Hb) {
    extern __shared__ char smem[];
    const int NK = MDIM / 64;                      // 16
    int bid = blockIdx.x;
    int swz = (bid & 7) * 320 + (bid >> 3);        // bijective (2560 % 8 == 0)
    int mt = swz % 10, nt = (swz / 10) & 31, e = swz / 320;
    const char* A  = (const char*)(Xb  + (size_t)e * GC * MDIM   + (size_t)mt * 256 * MDIM);
    const char* Bg = (const char*)(WgT + (size_t)e * HDIM * MDIM + (size_t)nt * 128 * MDIM);
    const char* B0 = (const char*)(W0T + (size_t)e * HDIM * MDIM + (size_t)nt * 128 * MDIM);
    int tid = threadIdx.x, w = tid >> 6, l = tid & 63;
    int wm = w >> 2, wn = w & 3;
    int lr = l & 31, lk = l >> 5;
    int lswz = ((lr >> 1) & 7) << 4;

    int koff[4];
    #pragma unroll
    for (int ks = 0; ks < 4; ++ks) koff[ks] = (ks * 32 + lk * 16) ^ lswz;
    int baseA[4];
    #pragma unroll
    for (int rb = 0; rb < 4; ++rb) baseA[rb] = (wm * 128 + rb * 32 + lr) * 128;
    int baseB = (wn * 32 + lr) * 128;

    const char* srcA[4]; const char* srcG[2]; const char* srcO[2];
    #pragma unroll
    for (int p = 0; p < 4; ++p) {
        int gr = p * 64 + w * 8 + (l >> 3);
        srcA[p] = A + (size_t)gr * (MDIM * 2) + (((l & 7) * 16) ^ swz128(gr));
    }
    #pragma unroll
    for (int p = 0; p < 2; ++p) {
        int gr = p * 64 + w * 8 + (l >> 3);
        srcG[p] = Bg + (size_t)gr * (MDIM * 2) + (((l & 7) * 16) ^ swz128(gr));
        srcO[p] = B0 + (size_t)gr * (MDIM * 2) + (((l & 7) * 16) ^ swz128(gr));
    }

    f32x16 zz;
    #pragma unroll
    for (int i = 0; i < 16; ++i) zz[i] = 0.f;
    f32x16 ag[4], ao[4];
    #pragma unroll
    for (int rb = 0; rb < 4; ++rb) { ag[rb] = zz; ao[rb] = zz; }

    auto stage = [&](int tt) {
        int kk = tt * 128;
        char* dst = smem + (tt & 1) * 65536;
        #pragma unroll
        for (int p = 0; p < 4; ++p)
            gload16(srcA[p] + kk, dst + (p * 64 + w * 8) * 128);
        #pragma unroll
        for (int p = 0; p < 2; ++p) {
            gload16(srcG[p] + kk, dst + 32768 + (p * 64 + w * 8) * 128);
            gload16(srcO[p] + kk, dst + 49152 + (p * 64 + w * 8) * 128);
        }
    };

    stage(0);
    asm volatile("s_waitcnt vmcnt(0)" ::: "memory");
    BAR();

    #pragma unroll 1
    for (int t = 0; t < NK; ++t) {
        if (t + 1 < NK) stage(t + 1);
        const char* bufc = smem + (t & 1) * 65536;
        #pragma unroll
        for (int ks = 0; ks < 4; ++ks) {
            bf16x8 bg = *(const bf16x8*)(bufc + 32768 + baseB + koff[ks]);
            bf16x8 bo = *(const bf16x8*)(bufc + 49152 + baseB + koff[ks]);
            bf16x8 af[4];
            #pragma unroll
            for (int rb = 0; rb < 4; ++rb)
                af[rb] = *(const bf16x8*)(bufc + baseA[rb] + koff[ks]);
            __builtin_amdgcn_s_setprio(1);
            #pragma unroll
            for (int rb = 0; rb < 4; ++rb) {
                ag[rb] = MFMA32(bg, af[rb], ag[rb]);
                ao[rb] = MFMA32(bo, af[rb], ao[rb]);
            }
            __builtin_amdgcn_s_setprio(0);
        }
        asm volatile("s_waitcnt vmcnt(0)" ::: "memory");
        BAR();
    }

    u16* He = Hb + (size_t)e * GC * HDIM;
    int row0 = mt * 256 + wm * 128 + lr;
    int col0 = nt * 128 + wn * 32 + lk * 4;
    #pragma unroll
    for (int rb = 0; rb < 4; ++rb) {
        size_t rowoff = (size_t)(row0 + rb * 32) * HDIM;
        #pragma unroll
        for (int q = 0; q < 4; ++q) {
            s16x4 pk;
            #pragma unroll
            for (int r = 0; r < 4; ++r) {
                float gv = ag[rb][q * 4 + r], ov = ao[rb][q * 4 + r];
                float hv = gv / (1.f + __expf(-gv)) * ov;
                pk[r] = (short)f2bf(hv);
            }
            *(s16x4*)(He + rowoff + col0 + q * 8) = pk;
        }
    }
}

// ======================================================================
// GEMM3 v10 (R14-proven geometry; EO now bf16): 32x32x16, BM=320 BN=256
// BK=64 -> 256 blocks = exactly 1/CU, zero tail. ring-2 LDS 144KiB.
// ======================================================================
__global__ __launch_bounds__(512, 1) void gemm_out_v10(
        const u16* __restrict__ Hb, const u16* __restrict__ WoT,
        u16* __restrict__ EO) {
    extern __shared__ char smem[];
    const int NK = HDIM / 64;                      // 64
    int bid = blockIdx.x;
    int swz = (bid & 7) * 32 + (bid >> 3);         // bijective (256 % 8 == 0)
    int e = swz >> 5; int rem = swz & 31; int mt = rem & 7; int nt = rem >> 3;
    const char* A = (const char*)(Hb  + (size_t)e * GC * HDIM   + (size_t)mt * 320 * HDIM);
    const char* B = (const char*)(WoT + (size_t)e * MDIM * HDIM + (size_t)nt * 256 * HDIM);
    int tid = threadIdx.x, w = tid >> 6, l = tid & 63;
    int wm = w >> 2, wn = w & 3;
    int lr = l & 31, lk = l >> 5;
    int lswz = ((lr >> 1) & 7) << 4;

    int koff[4];
    #pragma unroll
    for (int ks = 0; ks < 4; ++ks) koff[ks] = (ks * 32 + lk * 16) ^ lswz;
    int baseA[5], baseB[2];
    #pragma unroll
    for (int rb = 0; rb < 5; ++rb) baseA[rb] = (wm * 160 + rb * 32 + lr) * 128;
    #pragma unroll
    for (int cb = 0; cb < 2; ++cb) baseB[cb] = (wn * 64 + cb * 32 + lr) * 128;

    const char* srcA[5]; const char* srcB[4];
    #pragma unroll
    for (int p = 0; p < 5; ++p) {
        int gr = p * 64 + w * 8 + (l >> 3);
        srcA[p] = A + (size_t)gr * (HDIM * 2) + (((l & 7) * 16) ^ swz128(gr));
    }
    #pragma unroll
    for (int p = 0; p < 4; ++p) {
        int gr = p * 64 + w * 8 + (l >> 3);
        srcB[p] = B + (size_t)gr * (HDIM * 2) + (((l & 7) * 16) ^ swz128(gr));
    }

    f32x16 zz;
    #pragma unroll
    for (int i = 0; i < 16; ++i) zz[i] = 0.f;
    f32x16 acc[5][2];
    #pragma unroll
    for (int i = 0; i < 5; ++i)
        #pragma unroll
        for (int j = 0; j < 2; ++j) acc[i][j] = zz;

    auto stage = [&](int tt) {
        int kk = tt * 128;
        char* dst = smem + (tt & 1) * 73728;
        #pragma unroll
        for (int p = 0; p < 5; ++p)
            gload16(srcA[p] + kk, dst + (p * 64 + w * 8) * 128);
        #pragma unroll
        for (int p = 0; p < 4; ++p)
            gload16(srcB[p] + kk, dst + 40960 + (p * 64 + w * 8) * 128);
    };

    stage(0);
    asm volatile("s_waitcnt vmcnt(0)" ::: "memory");
    BAR();

    #pragma unroll 1
    for (int t = 0; t < NK; ++t) {
        if (t + 1 < NK) stage(t + 1);
        const char* bufc = smem + (t & 1) * 73728;
        #pragma unroll
        for (int ks = 0; ks < 4; ++ks) {
            bf16x8 bf[2], af[5];
            #pragma unroll
            for (int cb = 0; cb < 2; ++cb)
                bf[cb] = *(const bf16x8*)(bufc + 40960 + baseB[cb] + koff[ks]);
            #pragma unroll
            for (int rb = 0; rb < 5; ++rb)
                af[rb] = *(const bf16x8*)(bufc + baseA[rb] + koff[ks]);
            __builtin_amdgcn_s_setprio(1);
            #pragma unroll
            for (int rb = 0; rb < 5; ++rb)
                #pragma unroll
                for (int cb = 0; cb < 2; ++cb)
                    acc[rb][cb] = MFMA32(bf[cb], af[rb], acc[rb][cb]);
            __builtin_amdgcn_s_setprio(0);
        }
        asm volatile("s_waitcnt vmcnt(0)" ::: "memory");
        BAR();
    }

    u16* Ee = EO + (size_t)e * GC * MDIM;
    int row0 = mt * 320 + wm * 160 + lr;
    int col0 = nt * 256 + wn * 64 + lk * 4;
    #pragma unroll
    for (int rb = 0; rb < 5; ++rb) {
        size_t rowoff = (size_t)(row0 + rb * 32) * MDIM;
        #pragma unroll
        for (int cb = 0; cb < 2; ++cb)
            #pragma unroll
            for (int q = 0; q < 4; ++q) {
                s16x4 pk;
                #pragma unroll
                for (int r = 0; r < 4; ++r) pk[r] = (short)f2bf(acc[rb][cb][q * 4 + r]);
                *(s16x4*)(Ee + rowoff + col0 + cb * 32 + q * 8) = pk;
            }
    }
}

// ============ combine (blocks 0..8191, bf16 EO) + aux_final (8192) ==========
__global__ __launch_bounds__(256) void combine_aux_kernel(
        const u16* __restrict__ EO, const int* __restrict__ top_i,
        const float* __restrict__ top_p, const int* __restrict__ token_c,
        const float* __restrict__ sums, float* __restrict__ out) {
    int bid = blockIdx.x;
    if (bid == G * S) {
        if (threadIdx.x == 0) {
            float lb = 0.f, z = 0.f;
            for (int g = 0; g < G; ++g) {
                for (int e = 0; e < E; ++e)
                    lb += (sums[g*17 + 8 + e] / (float)S) * (sums[g*17 + e] / (float)S);
                z += sums[g*17 + 16];
            }
            lb = lb / (float)(G * E) * (float)(E * E);
            z /= (float)(G * S);
            out[(size_t)G * S * MDIM] = 0.01f * lb + 0.001f * z;
        }
        return;
    }
    int tok = bid, t = threadIdx.x;
    int g = tok >> 11;
    f32x4 acc = {0.f, 0.f, 0.f, 0.f};
    #pragma unroll
    for (int k = 0; k < 2; ++k) {
        int c = token_c[tok * 2 + k];
        if (c >= 0) {
            int e = top_i[tok * 2 + k];
            float p = top_p[tok * 2 + k];
            const u16* src = EO + ((size_t)e * GC + g * CAP + c) * MDIM + t * 4;
            s16x4 v = *(const s16x4*)src;
            #pragma unroll
            for (int j = 0; j < 4; ++j) acc[j] += p * bf2f((u16)v[j]);
        }
    }
    *(f32x4*)(out + (size_t)tok * MDIM + t * 4) = acc;
}

extern "C" void kernel_launch(void* const* d_in, const int* in_sizes, int n_in,
                              void* d_out, int out_size, void* d_ws, size_t ws_size,
                              hipStream_t stream) {
    (void)in_sizes; (void)n_in; (void)out_size; (void)ws_size;
    const float* inputs   = (const float*)d_in[0];
    const float* paddings = (const float*)d_in[1];
    const float* router_w = (const float*)d_in[2];
    const float* wi_gate  = (const float*)d_in[3];
    const float* wi_0     = (const float*)d_in[4];
    const float* wo       = (const float*)d_in[5];
    float* out = (float*)d_out;

    char* p = (char*)d_ws;
    u16* WgT = (u16*)p; p += (size_t)E * HDIM * MDIM * 2;
    u16* W0T = (u16*)p; p += (size_t)E * HDIM * MDIM * 2;
    u16* WoT = (u16*)p; p += (size_t)E * HDIM * MDIM * 2;
    u16* Xb  = (u16*)p; p += (size_t)E * GC * MDIM * 2;
    u16* Hb  = (u16*)p; p += (size_t)E * GC * HDIM * 2;
    u16* EO  = (u16*)p; p += (size_t)E * GC * MDIM * 2;
    int*   top_i = (int*)p;   p += (size_t)G * S * TOPK * 4;
    float* top_p = (float*)p; p += (size_t)G * S * TOPK * 4;
    int*   token_c = (int*)p; p += (size_t)G * S * TOPK * 4;
    int*   slot_token = (int*)p; p += (size_t)E * G * CAP * 4;
    float* partials = (float*)p; p += (size_t)RBLK * 17 * 4;
    float* sums = (float*)p; p += 4 * 17 * 4;

    hipFuncSetAttribute((const void*)gemm_ffn12_v9,
                        hipFuncAttributeMaxDynamicSharedMemorySize, 131072);
    hipFuncSetAttribute((const void*)gemm_out_v10,
                        hipFuncAttributeMaxDynamicSharedMemorySize, 147456);

    // router (2048) + wi_gate T (8192) + wi_0 T (8192) + wo T (8192)
    prep_kernel<<<RBLK + 24576, 256, 0, stream>>>(inputs, router_w, wi_gate, wi_0, wo,
                                                  WgT, W0T, WoT, top_i, top_p, partials);
    // scan (32, writes all -1 sentinels) + reduce_partials (4)
    scan_reduce_kernel<<<36, 256, 0, stream>>>(top_i, paddings, partials,
                                               slot_token, token_c, sums);
    gather_kernel<<<E * GC, 128, 0, stream>>>(inputs, slot_token, Xb);
    gemm_ffn12_v9<<<2560, 512, 131072, stream>>>(Xb, WgT, W0T, Hb);
    gemm_out_v10<<<256, 512, 147456, stream>>>(Hb, WoT, EO);
    // combine (8192) + aux_final (1)
    combine_aux_kernel<<<G * S + 1, 256, 0, stream>>>(EO, top_i, top_p, token_c,
                                                      sums, out);
}